// Round 1
// baseline (646.411 us; speedup 1.0000x reference)
//
#include <hip/hip_runtime.h>

#define NSTEPS 512
#define BATCH  65536
#define NOUT   (NSTEPS + 1)      // 513
#define TILE   32                // steps per LDS tile (double-buffered)
#define NTILES (NSTEPS / TILE)   // 16
#define PAD    34                // even stride: float2 LDS writes, <=2-way banks (free)

// Heston constants (float32, matching reference)
#define C_DT       (1.0f / 512.0f)
#define C_SQRT_DT  0.04419417382415922f      // sqrt(1/512)
#define C_RHO      (-0.7f)
#define C_RHOPERP  0.7141428428542850f       // sqrt(1 - 0.49)
#define C_V0       0.055225f                 // 0.235^2
#define C_THETA    0.04f
#define C_SIGMAV   2.0f
#define C_S0       100.0f
// KAPPA == 1.0 (folded into the drift term)

// Wave-specialized producer/consumer block:
//   wave 0  : serial V/logS recursion for 64 paths (1 path/lane), tiles of 32
//             steps into double-buffered LDS. Explicit 1-chunk Z prefetch.
//   waves1-3: read LDS, apply S0*exp(logS), store S and V transposed
//             (coalesced 128 B segments per row).
// Grid = 1024 blocks x 4 waves = 16 waves/CU (was 4) — the whole point.
// Sync: raw s_barrier + lgkmcnt-only waits; NO vmcnt drain, so producer loads
// and consumer stores stay in flight across tile boundaries.
__global__ __launch_bounds__(256, 4) void heston_paths_pc(
    const float* __restrict__ Zvol,   // [BATCH, NSTEPS, 2]
    const float* __restrict__ Zp,     // [BATCH, NSTEPS]
    float* __restrict__ S,            // [BATCH, NOUT]
    float* __restrict__ V)            // [BATCH, NOUT]
{
    __shared__ float Lt[2][64][PAD];  // running log-price (pre-exp)
    __shared__ float Vt[2][64][PAD];  // variance path

    const int tid      = threadIdx.x;
    const int w        = tid >> 6;        // wave 0 = producer, 1..3 = consumers
    const int lane     = tid & 63;
    const int pathBase = blockIdx.x * 64;
    const int b        = pathBase + lane;

    // ---- producer state (live registers only in wave 0) ----
    const float4* __restrict__ zv4 = (const float4*)(Zvol + (size_t)b * (NSTEPS * 2));
    const float4* __restrict__ zp4 = (const float4*)(Zp   + (size_t)b * NSTEPS);
    float v    = C_V0;
    float logS = 0.0f;
    float4 A0, A1, A2, A3, P0, P1;    // prefetch regs (chunk = 8 steps)
    if (w == 0) {
        A0 = zv4[0]; A1 = zv4[1]; A2 = zv4[2]; A3 = zv4[3];
        P0 = zp4[0]; P1 = zp4[1];
    }

    // ---- consumer constants ----
    const int cw     = w - 1;         // 0..2
    const int c_col  = lane & 31;     // column within tile
    const int c_row  = lane >> 5;     // row parity within a row-pair

    if (w == 1) {
        // column 0 (t=0); partial lines completed by tile-0 stores in L2
        S[(size_t)b * NOUT] = C_S0;
        V[(size_t)b * NOUT] = C_V0;
    }

    // consumer: drain one 64x32 tile of S (exp) and V from LDS buffer
    auto consume = [&](int tIdx) {
        const int buf = tIdx & 1;
        const int k0  = tIdx * TILE;
        for (int tau = cw; tau < 64; tau += 3) {   // 21-22 tasks/wave
            const int pair = tau & 31;             // row-pair index
            const int r    = pair * 2 + c_row;
            const size_t idx = (size_t)(pathBase + r) * NOUT + 1 + k0 + c_col;
            if (tau < 32) S[idx] = C_S0 * __expf(Lt[buf][r][c_col]);
            else          V[idx] = Vt[buf][r][c_col];
        }
    };

    for (int t = 0; t < NTILES; ++t) {
        if (w == 0) {
            // -------- produce tile t into buf (t&1) --------
            const int buf = t & 1;
            #pragma unroll
            for (int cc = 0; cc < 4; ++cc) {       // 4 chunks x 8 steps
                const int g = t * 4 + cc;          // global chunk id 0..63
                const float4 a0 = A0, a1 = A1, a2 = A2, a3 = A3;
                const float4 p0 = P0, p1 = P1;
                if (g + 1 < 4 * NTILES) {          // issue next chunk's loads NOW
                    const int q = (g + 1) * 4;
                    A0 = zv4[q + 0]; A1 = zv4[q + 1];
                    A2 = zv4[q + 2]; A3 = zv4[q + 3];
                    P0 = zp4[(g + 1) * 2 + 0]; P1 = zp4[(g + 1) * 2 + 1];
                }
                const float zv[8] = {a0.x, a0.z, a1.x, a1.z, a2.x, a2.z, a3.x, a3.z};
                const float zp[8] = {p0.x, p0.y, p0.z, p0.w, p1.x, p1.y, p1.z, p1.w};
                float lg[8], vn[8];
                #pragma unroll
                for (int j = 0; j < 8; ++j) {      // identical op order to baseline
                    const float vpos  = fmaxf(v, 0.0f);
                    float vnext = v + (C_THETA - vpos) * C_DT
                                    + C_SIGMAV * sqrtf(vpos * C_DT) * zv[j];
                    vnext = fmaxf(vnext, 0.0f);
                    const float dB = C_RHO * C_SQRT_DT * zv[j]
                                   + C_RHOPERP * C_SQRT_DT * zp[j];
                    logS += -0.5f * vpos * C_DT + sqrtf(vpos) * dB;
                    lg[j] = logS;
                    vn[j] = vnext;
                    v = vnext;
                }
                const int kk = cc * 8;
                #pragma unroll
                for (int j = 0; j < 8; j += 2) {   // ds_write_b64, 2-way banks: free
                    *(float2*)&Lt[buf][lane][kk + j] = make_float2(lg[j], lg[j + 1]);
                    *(float2*)&Vt[buf][lane][kk + j] = make_float2(vn[j], vn[j + 1]);
                }
            }
        } else if (t > 0) {
            consume(t - 1);                        // overlaps producer's tile t
        }
        // LDS ops retired; loads/stores stay in flight (no vmcnt drain)
        asm volatile("s_waitcnt lgkmcnt(0)" ::: "memory");
        __builtin_amdgcn_s_barrier();
        asm volatile("" ::: "memory");             // fence: no ds hoist above barrier
    }
    if (w > 0) consume(NTILES - 1);                // drain last tile
}

extern "C" void kernel_launch(void* const* d_in, const int* in_sizes, int n_in,
                              void* d_out, int out_size, void* d_ws, size_t ws_size,
                              hipStream_t stream) {
    const float* Zvol = (const float*)d_in[0];   // [65536, 512, 2] f32
    const float* Zp   = (const float*)d_in[1];   // [65536, 512] f32
    float* S = (float*)d_out;                                  // [65536, 513]
    float* V = S + (size_t)BATCH * NOUT;                       // [65536, 513]

    heston_paths_pc<<<BATCH / 64, 256, 0, stream>>>(Zvol, Zp, S, V);
}